// Round 26
// baseline (355.441 us; speedup 1.0000x reference)
//
#include <hip/hip_runtime.h>
#include <math.h>

#define EPSV 1e-8f

constexpr int BB = 128;   // batch
constexpr int NROW = 512; // words = regions = 512
constexpr int DT = 300;   // text embed
constexpr int DI = 1024;  // image embed
constexpr int DD = 256;   // joint dim
constexpr int NB = (BB * NROW) / 128;  // 512 row-blocks per tensor (128-row)

typedef __bf16 bf16x8 __attribute__((ext_vector_type(8)));
typedef float f32x4 __attribute__((ext_vector_type(4)));

__device__ inline unsigned short f2bf(float f) {
  unsigned int x = __builtin_bit_cast(unsigned int, f);
  unsigned int r = (x + 0x7fffu + ((x >> 16) & 1u)) >> 16;
  return (unsigned short)r;
}
__device__ inline float bf2f(unsigned short u) {
  return __builtin_bit_cast(float, (unsigned int)u << 16);
}

// ---------------------------------------------------------------------------
// W [E][256] f32  ->  Wt [256][Ep] bf16, zero-padded cols E..Ep.  (linear)
// ---------------------------------------------------------------------------
__global__ __launch_bounds__(256) void prep_w(
    const float* __restrict__ W, unsigned short* __restrict__ Wt, int E, int Ep) {
  __shared__ float tile[32][36];
  const int t = threadIdx.x;
  const int e0 = blockIdx.x * 32, n0 = blockIdx.y * 32;
  {
    const int r = t >> 3, c4 = (t & 7) * 4;
    float4 v = {0.f, 0.f, 0.f, 0.f};
    if (e0 + r < E) v = *reinterpret_cast<const float4*>(&W[(size_t)(e0 + r) * DD + n0 + c4]);
    tile[r][c4] = v.x; tile[r][c4 + 1] = v.y; tile[r][c4 + 2] = v.z; tile[r][c4 + 3] = v.w;
  }
  __syncthreads();
  {
    const int n = t >> 3, e4 = (t & 7) * 4;
    uint2 pk;
    pk.x = f2bf(tile[e4][n]) | ((unsigned)f2bf(tile[e4 + 1][n]) << 16);
    pk.y = f2bf(tile[e4 + 2][n]) | ((unsigned)f2bf(tile[e4 + 3][n]) << 16);
    *reinterpret_cast<uint2*>(&Wt[(size_t)(n0 + n) * Ep + e0 + e4]) = pk;
  }
}

// ---------------------------------------------------------------------------
// Fused MFMA projection, 128-row tiles (image blocks 0..511, text 512..1023).
// (R25 measured best — unchanged.)
// ---------------------------------------------------------------------------
__global__ __launch_bounds__(512, 4) void proj_mfma_fused(
    const float* __restrict__ Xi, const float* __restrict__ Xt,
    const unsigned short* __restrict__ Wti, const unsigned short* __restrict__ Wtt,
    const float* __restrict__ bi, const float* __restrict__ bt,
    unsigned short* __restrict__ Ybi, unsigned short* __restrict__ Yti,
    unsigned short* __restrict__ Ybt, unsigned short* __restrict__ Ytt) {
  __shared__ __align__(16) unsigned char smem[32768];
  unsigned short* Xs = (unsigned short*)smem;            // [128][40] bf16 staging
  unsigned short* Ws = (unsigned short*)(smem + 10240);  // [256][40] bf16 staging
  float* red2 = (float*)smem;                            // [128][4] (after barrier A)
  unsigned short* rp = (unsigned short*)smem;            // [64][256] (two passes)

  const bool isImg = blockIdx.x < NB;  // image (long) blocks scheduled first
  const float* X = isImg ? Xi : Xt;
  const unsigned short* Wt = isImg ? Wti : Wtt;
  const float* bias = isImg ? bi : bt;
  unsigned short* Yb = isImg ? Ybi : Ybt;
  unsigned short* Yt = isImg ? Yti : Ytt;
  const int E = isImg ? DI : DT;
  const int Ep = isImg ? 1024 : 320;
  const int row0 = (isImg ? blockIdx.x : blockIdx.x - NB) * 128;

  const int t = threadIdx.x;
  const int l = t & 63, w = t >> 6;
  const int q15 = l & 15, h = l >> 4;
  const int wrow = w >> 2, wcol = w & 3;

  f32x4 acc[4][4];
#pragma unroll
  for (int rt = 0; rt < 4; ++rt)
#pragma unroll
    for (int ct = 0; ct < 4; ++ct) acc[rt][ct] = (f32x4){0.f, 0.f, 0.f, 0.f};

  const int sxr = t >> 2, sxq = t & 3;  // X staging: row 0..127, col-quad 0..3
  const int swn = t >> 1, swh = t & 1;  // W staging: n 0..255, half 0..1

  for (int e0 = 0; e0 < Ep; e0 += 32) {
    __syncthreads();
    {  // stage X chunk 128x32 f32 -> bf16 (8 f32/thread)
      const int eb = e0 + sxq * 8;
      float4 a = {0.f, 0.f, 0.f, 0.f}, b4 = {0.f, 0.f, 0.f, 0.f};
      const float* xp = &X[(size_t)(row0 + sxr) * E + eb];
      if (eb + 4 <= E) a = *reinterpret_cast<const float4*>(xp);
      if (eb + 8 <= E) b4 = *reinterpret_cast<const float4*>(xp + 4);
      uint4 u;
      u.x = f2bf(a.x) | ((unsigned)f2bf(a.y) << 16);
      u.y = f2bf(a.z) | ((unsigned)f2bf(a.w) << 16);
      u.z = f2bf(b4.x) | ((unsigned)f2bf(b4.y) << 16);
      u.w = f2bf(b4.z) | ((unsigned)f2bf(b4.w) << 16);
      *reinterpret_cast<uint4*>(&Xs[sxr * 40 + sxq * 8]) = u;
    }
    {  // stage Wt chunk 256x32 bf16: 2 x uint4 per thread
      const unsigned short* wp = &Wt[(size_t)swn * Ep + e0 + swh * 16];
      const uint4 u0 = *reinterpret_cast<const uint4*>(wp);
      const uint4 u1 = *reinterpret_cast<const uint4*>(wp + 8);
      *reinterpret_cast<uint4*>(&Ws[swn * 40 + swh * 16]) = u0;
      *reinterpret_cast<uint4*>(&Ws[swn * 40 + swh * 16 + 8]) = u1;
    }
    __syncthreads();
    bf16x8 af[4], bfr[4];
#pragma unroll
    for (int rt = 0; rt < 4; ++rt)
      af[rt] = *reinterpret_cast<const bf16x8*>(&Xs[(wrow * 64 + rt * 16 + q15) * 40 + h * 8]);
#pragma unroll
    for (int ct = 0; ct < 4; ++ct)
      bfr[ct] = *reinterpret_cast<const bf16x8*>(&Ws[(wcol * 64 + ct * 16 + q15) * 40 + h * 8]);
#pragma unroll
    for (int rt = 0; rt < 4; ++rt)
#pragma unroll
      for (int ct = 0; ct < 4; ++ct)
        acc[rt][ct] = __builtin_amdgcn_mfma_f32_16x16x32_bf16(af[rt], bfr[ct], acc[rt][ct], 0, 0, 0);
  }

  // ---- epilogue: bias, cross-wave L2 norm, dual-layout bf16 stores ----
  float bias_v[4];
#pragma unroll
  for (int ct = 0; ct < 4; ++ct) bias_v[ct] = bias[wcol * 64 + ct * 16 + q15];
#pragma unroll
  for (int rt = 0; rt < 4; ++rt)
#pragma unroll
    for (int ct = 0; ct < 4; ++ct)
#pragma unroll
      for (int r = 0; r < 4; ++r) acc[rt][ct][r] += bias_v[ct];

  float ss[4][4];
#pragma unroll
  for (int rt = 0; rt < 4; ++rt)
#pragma unroll
    for (int r = 0; r < 4; ++r) {
      float s = 0.f;
#pragma unroll
      for (int ct = 0; ct < 4; ++ct) s = fmaf(acc[rt][ct][r], acc[rt][ct][r], s);
      s += __shfl_xor(s, 1, 64);
      s += __shfl_xor(s, 2, 64);
      s += __shfl_xor(s, 4, 64);
      s += __shfl_xor(s, 8, 64);
      ss[rt][r] = s;
    }

  __syncthreads();  // A: staging LDS dead -> red2 region valid
  if (q15 == 0) {
#pragma unroll
    for (int rt = 0; rt < 4; ++rt)
#pragma unroll
      for (int r = 0; r < 4; ++r)
        red2[(wrow * 64 + rt * 16 + h * 4 + r) * 4 + wcol] = ss[rt][r];
  }
  __syncthreads();  // B
  float inv[4][4];
#pragma unroll
  for (int rt = 0; rt < 4; ++rt)
#pragma unroll
    for (int r = 0; r < 4; ++r) {
      const float4 p = *reinterpret_cast<const float4*>(&red2[(wrow * 64 + rt * 16 + h * 4 + r) * 4]);
      inv[rt][r] = 1.f / (sqrtf(p.x + p.y + p.z + p.w) + EPSV);
    }
  __syncthreads();  // C: red2 dead -> rp region valid

  const int bb = row0 >> 9;
  const int rin0 = row0 & 511;
  // Yt (transposed) stores: packed b64, all threads
#pragma unroll
  for (int rt = 0; rt < 4; ++rt) {
#pragma unroll
    for (int ct = 0; ct < 4; ++ct) {
      unsigned short uv[4];
#pragma unroll
      for (int r = 0; r < 4; ++r) uv[r] = f2bf(acc[rt][ct][r] * inv[rt][r]);
      const int col = wcol * 64 + ct * 16 + q15;
      unsigned long long pk = (unsigned long long)uv[0] |
                              ((unsigned long long)uv[1] << 16) |
                              ((unsigned long long)uv[2] << 32) |
                              ((unsigned long long)uv[3] << 48);
      const int rin = rin0 + wrow * 64 + rt * 16 + h * 4;
      *reinterpret_cast<unsigned long long*>(&Yt[((size_t)bb * DD + col) * NROW + rin]) = pk;
    }
  }
  // Yb (row-major) via two 64-row repack passes (rp = 32 KB)
#pragma unroll
  for (int pass = 0; pass < 2; ++pass) {
    if (wrow == pass) {
#pragma unroll
      for (int rt = 0; rt < 4; ++rt)
#pragma unroll
        for (int ct = 0; ct < 4; ++ct) {
          const int col = wcol * 64 + ct * 16 + q15;
#pragma unroll
          for (int r = 0; r < 4; ++r)
            rp[(rt * 16 + h * 4 + r) * 256 + col] = f2bf(acc[rt][ct][r] * inv[rt][r]);
        }
    }
    __syncthreads();  // rp rows complete
#pragma unroll
    for (int i = 0; i < 4; ++i) {
      const int s = t + i * 512;           // 2048 uint4 = 64 rows x 32
      const int row = s >> 5, c = s & 31;
      const uint4 v = *reinterpret_cast<const uint4*>(&rp[row * 256 + c * 8]);
      *reinterpret_cast<uint4*>(&Yb[(size_t)(row0 + pass * 64 + row) * DD + c * 8]) = v;
    }
    __syncthreads();  // rp free for next pass
  }
}

// ---------------------------------------------------------------------------
// Fused MFMA flash cross-attention, both directions in one dispatch.
// R26: __launch_bounds__(256, 4) (regs 130 -> 128, R24-proven safe) and
// pads trimmed (K_lds 264->260, Vt/P 40->36) so LDS = 39.1 KB x 4 = 156.3
// <= 160 KB -> 4 blocks/CU = 16 waves/CU (was 3).  R23 showed attention
// responds to resident-block TLP.
// ---------------------------------------------------------------------------
__global__ __launch_bounds__(256, 4) void cross_attn_fused(
    const unsigned short* __restrict__ tf,   // [b][row][256] bf16
    const unsigned short* __restrict__ imf,  // [b][row][256] bf16
    const unsigned short* __restrict__ tft,  // [b][256][row] bf16
    const unsigned short* __restrict__ imft, // [b][256][row] bf16
    float* __restrict__ out, float invN) {
  __shared__ __align__(16) unsigned short K_lds[32 * 260];    // pad 256+4
  __shared__ __align__(16) unsigned short Vt_lds[256 * 36];   // pad 32+4
  __shared__ __align__(16) unsigned short P_lds[4][16 * 36];  // per-wave

  const int dir = blockIdx.z;
  const unsigned short* Qg  = dir ? imf : tf;
  const unsigned short* Kg  = dir ? tf : imf;
  const unsigned short* Vtg = dir ? tft : imft;

  const int t = threadIdx.x;
  const int l = t & 63;
  const int w = t >> 6;              // 4 waves
  const int h = l >> 4;
  const int q15 = l & 15;
  const int b = blockIdx.x;          // b-major: same-b blocks -> same XCD
  const int qbase = blockIdx.y * 64 + w * 16;
  const size_t qrow0 = (size_t)b * NROW + qbase;
  const size_t kband = (size_t)b * NROW * DD;
  const size_t vband = (size_t)b * DD * NROW;

  // Q fragments: lane holds Q[q15][kc*32 + h*8 + j]
  bf16x8 qf[8];
#pragma unroll
  for (int kc = 0; kc < 8; ++kc)
    qf[kc] = *reinterpret_cast<const bf16x8*>(
        &Qg[(qrow0 + q15) * DD + kc * 32 + h * 8]);

  f32x4 accO[16];
#pragma unroll
  for (int nt = 0; nt < 16; ++nt) accO[nt] = (f32x4){0.f, 0.f, 0.f, 0.f};
  float denom = 0.f;
  float dotq = 0.f;

  for (int c0 = 0; c0 < NROW; c0 += 32) {
    __syncthreads();  // A: all waves done reading previous chunk
#pragma unroll
    for (int i = 0; i < 4; ++i) {  // stage K chunk 32x256 (1024 uint4 / 256 thr)
      const int slot = t + i * 256;
      const int row = slot >> 5, cc = slot & 31;
      const uint4 v = *reinterpret_cast<const uint4*>(
          &Kg[kband + (size_t)(c0 + row) * DD + cc * 8]);
      *reinterpret_cast<uint4*>(&K_lds[row * 260 + cc * 8]) = v;
    }
#pragma unroll
    for (int i = 0; i < 4; ++i) {  // stage Vt chunk 256x32
      const int slot = t + i * 256;
      const int d = slot >> 2, cc = slot & 3;
      const uint4 v = *reinterpret_cast<const uint4*>(
          &Vtg[vband + (size_t)d * NROW + c0 + cc * 8]);
      *reinterpret_cast<uint4*>(&Vt_lds[d * 36 + cc * 8]) = v;
    }
    __syncthreads();  // B: chunk visible

    // ---- swapped QK^T: lane holds S[q=q15][kv=kvt*16+4h+r]
    f32x4 accS[2];
#pragma unroll
    for (int kvt = 0; kvt < 2; ++kvt) accS[kvt] = (f32x4){0.f, 0.f, 0.f, 0.f};
#pragma unroll
    for (int kc = 0; kc < 8; ++kc) {
#pragma unroll
      for (int kvt = 0; kvt < 2; ++kvt) {
        const bf16x8 kf = *reinterpret_cast<const bf16x8*>(
            &K_lds[(kvt * 16 + q15) * 260 + kc * 32 + h * 8]);
        accS[kvt] = __builtin_amdgcn_mfma_f32_16x16x32_bf16(
            kf, qf[kc], accS[kvt], 0, 0, 0);
      }
    }

    // ---- leaky + exp(9a-9); accumulate denom and dot(q,O) = sum p*s_raw
#pragma unroll
    for (int kvt = 0; kvt < 2; ++kvt) {
      float p[4];
#pragma unroll
      for (int r = 0; r < 4; ++r) {
        const float s = accS[kvt][r];
        const float a = (s > 0.f) ? s : 0.1f * s;
        p[r] = __expf(9.f * a - 9.f);
        denom += p[r];
        dotq = fmaf(p[r], s, dotq);
      }
      uint2 pk;
      pk.x = f2bf(p[0]) | ((unsigned)f2bf(p[1]) << 16);
      pk.y = f2bf(p[2]) | ((unsigned)f2bf(p[3]) << 16);
      *reinterpret_cast<uint2*>(
          &P_lds[w][q15 * 36 + kvt * 16 + h * 4]) = pk;
    }

    // ---- PV: O[q][d] += P(16q x 32kv) . V(32kv x 256d)
    const bf16x8 pf = *reinterpret_cast<const bf16x8*>(
        &P_lds[w][q15 * 36 + h * 8]);
#pragma unroll
    for (int nt = 0; nt < 16; ++nt) {
      const bf16x8 vf = *reinterpret_cast<const bf16x8*>(
          &Vt_lds[(nt * 16 + q15) * 36 + h * 8]);
      accO[nt] = __builtin_amdgcn_mfma_f32_16x16x32_bf16(
          pf, vf, accO[nt], 0, 0, 0);
    }
  }

  // ---- epilogue: cos = dotq / (||O|| + denom*eps); mean; atomic
  denom += __shfl_xor(denom, 16, 64);
  denom += __shfl_xor(denom, 32, 64);
  dotq += __shfl_xor(dotq, 16, 64);
  dotq += __shfl_xor(dotq, 32, 64);
  float total = 0.f;
#pragma unroll
  for (int r = 0; r < 4; ++r) {
    float o2 = 0.f;
#pragma unroll
    for (int nt = 0; nt < 16; ++nt) {
      const float ov = accO[nt][r];
      o2 = fmaf(ov, ov, o2);
    }
#pragma unroll
    for (int off = 1; off < 16; off <<= 1) o2 += __shfl_xor(o2, off, 64);
    const int qrow = h * 4 + r;  // q15-index of this C-row's q within tile
    const float dnq = __shfl(denom, qrow, 64);
    const float dq  = __shfl(dotq, qrow, 64);
    total += dq / (sqrtf(o2) + dnq * EPSV);
  }
  total += __shfl_xor(total, 16, 64);
  total += __shfl_xor(total, 32, 64);
  if (l == 0) atomicAdd(&out[b], invN * total);
}

// ---------------------------------------------------------------------------
extern "C" void kernel_launch(void* const* d_in, const int* in_sizes, int n_in,
                              void* d_out, int out_size, void* d_ws, size_t ws_size,
                              hipStream_t stream) {
  const float* text  = (const float*)d_in[0];
  const float* image = (const float*)d_in[1];
  const float* Wt    = (const float*)d_in[2];
  const float* bt    = (const float*)d_in[3];
  const float* Wi    = (const float*)d_in[4];
  const float* bi    = (const float*)d_in[5];
  float* out = (float*)d_out;

  constexpr size_t NE = (size_t)BB * NROW * DD;
  unsigned short* tf   = (unsigned short*)d_ws;  // bf16 row-major
  unsigned short* imf  = tf + NE;
  unsigned short* tft  = imf + NE;               // bf16 [b][d][row]
  unsigned short* imft = tft + NE;
  unsigned short* wtt  = imft + NE;              // Wt text  [256][320]
  unsigned short* wti  = wtt + (size_t)DD * 320; // Wt image [256][1024]

  hipMemsetAsync(out, 0, sizeof(float) * BB, stream);

  prep_w<<<dim3(320 / 32, 8), 256, 0, stream>>>(Wt, wtt, DT, 320);
  prep_w<<<dim3(1024 / 32, 8), 256, 0, stream>>>(Wi, wti, DI, 1024);

  // one projection dispatch: image blocks [0,512) first, text [512,1024)
  proj_mfma_fused<<<dim3(2 * NB), 512, 0, stream>>>(
      image, text, wti, wtt, bi, bt, imf, imft, tf, tft);

  // one attention dispatch, both directions, 4-wave blocks, b-major XCD map
  cross_attn_fused<<<dim3(BB, NROW / 64, 2), 256, 0, stream>>>(
      tf, imf, tft, imft, out, 1.0f / NROW);
}

// Round 27
// 267.232 us; speedup vs baseline: 1.3301x; 1.3301x over previous
//
#include <hip/hip_runtime.h>
#include <math.h>

#define EPSV 1e-8f

constexpr int BB = 128;   // batch
constexpr int NROW = 512; // words = regions = 512
constexpr int DT = 300;   // text embed
constexpr int DI = 1024;  // image embed
constexpr int DD = 256;   // joint dim
constexpr int NB = (BB * NROW) / 128;  // 512 row-blocks per tensor (128-row)

typedef __bf16 bf16x8 __attribute__((ext_vector_type(8)));
typedef float f32x4 __attribute__((ext_vector_type(4)));

__device__ inline unsigned short f2bf(float f) {
  unsigned int x = __builtin_bit_cast(unsigned int, f);
  unsigned int r = (x + 0x7fffu + ((x >> 16) & 1u)) >> 16;
  return (unsigned short)r;
}
__device__ inline float bf2f(unsigned short u) {
  return __builtin_bit_cast(float, (unsigned int)u << 16);
}

// ---------------------------------------------------------------------------
// W [E][256] f32  ->  Wt [256][Ep] bf16, zero-padded cols E..Ep.  (linear)
// ---------------------------------------------------------------------------
__global__ __launch_bounds__(256) void prep_w(
    const float* __restrict__ W, unsigned short* __restrict__ Wt, int E, int Ep) {
  __shared__ float tile[32][36];
  const int t = threadIdx.x;
  const int e0 = blockIdx.x * 32, n0 = blockIdx.y * 32;
  {
    const int r = t >> 3, c4 = (t & 7) * 4;
    float4 v = {0.f, 0.f, 0.f, 0.f};
    if (e0 + r < E) v = *reinterpret_cast<const float4*>(&W[(size_t)(e0 + r) * DD + n0 + c4]);
    tile[r][c4] = v.x; tile[r][c4 + 1] = v.y; tile[r][c4 + 2] = v.z; tile[r][c4 + 3] = v.w;
  }
  __syncthreads();
  {
    const int n = t >> 3, e4 = (t & 7) * 4;
    uint2 pk;
    pk.x = f2bf(tile[e4][n]) | ((unsigned)f2bf(tile[e4 + 1][n]) << 16);
    pk.y = f2bf(tile[e4 + 2][n]) | ((unsigned)f2bf(tile[e4 + 3][n]) << 16);
    *reinterpret_cast<uint2*>(&Wt[(size_t)(n0 + n) * Ep + e0 + e4]) = pk;
  }
}

// ---------------------------------------------------------------------------
// Fused MFMA projection, 128-row tiles (image blocks 0..511, text 512..1023).
// (R25 measured best — unchanged.)
// ---------------------------------------------------------------------------
__global__ __launch_bounds__(512, 4) void proj_mfma_fused(
    const float* __restrict__ Xi, const float* __restrict__ Xt,
    const unsigned short* __restrict__ Wti, const unsigned short* __restrict__ Wtt,
    const float* __restrict__ bi, const float* __restrict__ bt,
    unsigned short* __restrict__ Ybi, unsigned short* __restrict__ Yti,
    unsigned short* __restrict__ Ybt, unsigned short* __restrict__ Ytt) {
  __shared__ __align__(16) unsigned char smem[32768];
  unsigned short* Xs = (unsigned short*)smem;            // [128][40] bf16 staging
  unsigned short* Ws = (unsigned short*)(smem + 10240);  // [256][40] bf16 staging
  float* red2 = (float*)smem;                            // [128][4] (after barrier A)
  unsigned short* rp = (unsigned short*)smem;            // [64][256] (two passes)

  const bool isImg = blockIdx.x < NB;  // image (long) blocks scheduled first
  const float* X = isImg ? Xi : Xt;
  const unsigned short* Wt = isImg ? Wti : Wtt;
  const float* bias = isImg ? bi : bt;
  unsigned short* Yb = isImg ? Ybi : Ybt;
  unsigned short* Yt = isImg ? Yti : Ytt;
  const int E = isImg ? DI : DT;
  const int Ep = isImg ? 1024 : 320;
  const int row0 = (isImg ? blockIdx.x : blockIdx.x - NB) * 128;

  const int t = threadIdx.x;
  const int l = t & 63, w = t >> 6;
  const int q15 = l & 15, h = l >> 4;
  const int wrow = w >> 2, wcol = w & 3;

  f32x4 acc[4][4];
#pragma unroll
  for (int rt = 0; rt < 4; ++rt)
#pragma unroll
    for (int ct = 0; ct < 4; ++ct) acc[rt][ct] = (f32x4){0.f, 0.f, 0.f, 0.f};

  const int sxr = t >> 2, sxq = t & 3;  // X staging: row 0..127, col-quad 0..3
  const int swn = t >> 1, swh = t & 1;  // W staging: n 0..255, half 0..1

  for (int e0 = 0; e0 < Ep; e0 += 32) {
    __syncthreads();
    {  // stage X chunk 128x32 f32 -> bf16 (8 f32/thread)
      const int eb = e0 + sxq * 8;
      float4 a = {0.f, 0.f, 0.f, 0.f}, b4 = {0.f, 0.f, 0.f, 0.f};
      const float* xp = &X[(size_t)(row0 + sxr) * E + eb];
      if (eb + 4 <= E) a = *reinterpret_cast<const float4*>(xp);
      if (eb + 8 <= E) b4 = *reinterpret_cast<const float4*>(xp + 4);
      uint4 u;
      u.x = f2bf(a.x) | ((unsigned)f2bf(a.y) << 16);
      u.y = f2bf(a.z) | ((unsigned)f2bf(a.w) << 16);
      u.z = f2bf(b4.x) | ((unsigned)f2bf(b4.y) << 16);
      u.w = f2bf(b4.z) | ((unsigned)f2bf(b4.w) << 16);
      *reinterpret_cast<uint4*>(&Xs[sxr * 40 + sxq * 8]) = u;
    }
    {  // stage Wt chunk 256x32 bf16: 2 x uint4 per thread
      const unsigned short* wp = &Wt[(size_t)swn * Ep + e0 + swh * 16];
      const uint4 u0 = *reinterpret_cast<const uint4*>(wp);
      const uint4 u1 = *reinterpret_cast<const uint4*>(wp + 8);
      *reinterpret_cast<uint4*>(&Ws[swn * 40 + swh * 16]) = u0;
      *reinterpret_cast<uint4*>(&Ws[swn * 40 + swh * 16 + 8]) = u1;
    }
    __syncthreads();
    bf16x8 af[4], bfr[4];
#pragma unroll
    for (int rt = 0; rt < 4; ++rt)
      af[rt] = *reinterpret_cast<const bf16x8*>(&Xs[(wrow * 64 + rt * 16 + q15) * 40 + h * 8]);
#pragma unroll
    for (int ct = 0; ct < 4; ++ct)
      bfr[ct] = *reinterpret_cast<const bf16x8*>(&Ws[(wcol * 64 + ct * 16 + q15) * 40 + h * 8]);
#pragma unroll
    for (int rt = 0; rt < 4; ++rt)
#pragma unroll
      for (int ct = 0; ct < 4; ++ct)
        acc[rt][ct] = __builtin_amdgcn_mfma_f32_16x16x32_bf16(af[rt], bfr[ct], acc[rt][ct], 0, 0, 0);
  }

  // ---- epilogue: bias, cross-wave L2 norm, dual-layout bf16 stores ----
  float bias_v[4];
#pragma unroll
  for (int ct = 0; ct < 4; ++ct) bias_v[ct] = bias[wcol * 64 + ct * 16 + q15];
#pragma unroll
  for (int rt = 0; rt < 4; ++rt)
#pragma unroll
    for (int ct = 0; ct < 4; ++ct)
#pragma unroll
      for (int r = 0; r < 4; ++r) acc[rt][ct][r] += bias_v[ct];

  float ss[4][4];
#pragma unroll
  for (int rt = 0; rt < 4; ++rt)
#pragma unroll
    for (int r = 0; r < 4; ++r) {
      float s = 0.f;
#pragma unroll
      for (int ct = 0; ct < 4; ++ct) s = fmaf(acc[rt][ct][r], acc[rt][ct][r], s);
      s += __shfl_xor(s, 1, 64);
      s += __shfl_xor(s, 2, 64);
      s += __shfl_xor(s, 4, 64);
      s += __shfl_xor(s, 8, 64);
      ss[rt][r] = s;
    }

  __syncthreads();  // A: staging LDS dead -> red2 region valid
  if (q15 == 0) {
#pragma unroll
    for (int rt = 0; rt < 4; ++rt)
#pragma unroll
      for (int r = 0; r < 4; ++r)
        red2[(wrow * 64 + rt * 16 + h * 4 + r) * 4 + wcol] = ss[rt][r];
  }
  __syncthreads();  // B
  float inv[4][4];
#pragma unroll
  for (int rt = 0; rt < 4; ++rt)
#pragma unroll
    for (int r = 0; r < 4; ++r) {
      const float4 p = *reinterpret_cast<const float4*>(&red2[(wrow * 64 + rt * 16 + h * 4 + r) * 4]);
      inv[rt][r] = 1.f / (sqrtf(p.x + p.y + p.z + p.w) + EPSV);
    }
  __syncthreads();  // C: red2 dead -> rp region valid

  const int bb = row0 >> 9;
  const int rin0 = row0 & 511;
  // Yt (transposed) stores: packed b64, all threads
#pragma unroll
  for (int rt = 0; rt < 4; ++rt) {
#pragma unroll
    for (int ct = 0; ct < 4; ++ct) {
      unsigned short uv[4];
#pragma unroll
      for (int r = 0; r < 4; ++r) uv[r] = f2bf(acc[rt][ct][r] * inv[rt][r]);
      const int col = wcol * 64 + ct * 16 + q15;
      unsigned long long pk = (unsigned long long)uv[0] |
                              ((unsigned long long)uv[1] << 16) |
                              ((unsigned long long)uv[2] << 32) |
                              ((unsigned long long)uv[3] << 48);
      const int rin = rin0 + wrow * 64 + rt * 16 + h * 4;
      *reinterpret_cast<unsigned long long*>(&Yt[((size_t)bb * DD + col) * NROW + rin]) = pk;
    }
  }
  // Yb (row-major) via two 64-row repack passes (rp = 32 KB)
#pragma unroll
  for (int pass = 0; pass < 2; ++pass) {
    if (wrow == pass) {
#pragma unroll
      for (int rt = 0; rt < 4; ++rt)
#pragma unroll
        for (int ct = 0; ct < 4; ++ct) {
          const int col = wcol * 64 + ct * 16 + q15;
#pragma unroll
          for (int r = 0; r < 4; ++r)
            rp[(rt * 16 + h * 4 + r) * 256 + col] = f2bf(acc[rt][ct][r] * inv[rt][r]);
        }
    }
    __syncthreads();  // rp rows complete
#pragma unroll
    for (int i = 0; i < 4; ++i) {
      const int s = t + i * 512;           // 2048 uint4 = 64 rows x 32
      const int row = s >> 5, c = s & 31;
      const uint4 v = *reinterpret_cast<const uint4*>(&rp[row * 256 + c * 8]);
      *reinterpret_cast<uint4*>(&Yb[(size_t)(row0 + pass * 64 + row) * DD + c * 8]) = v;
    }
    __syncthreads();  // rp free for next pass
  }
}

// ---------------------------------------------------------------------------
// Fused MFMA flash cross-attention, both directions in one dispatch.
// (R23/R25 measured best: 4 waves / 64-query tiles, pads 264/40 — 16B
// aligned.  R26's pad trim to 260/36 broke b128 alignment: refuted.)
// ---------------------------------------------------------------------------
__global__ __launch_bounds__(256, 3) void cross_attn_fused(
    const unsigned short* __restrict__ tf,   // [b][row][256] bf16
    const unsigned short* __restrict__ imf,  // [b][row][256] bf16
    const unsigned short* __restrict__ tft,  // [b][256][row] bf16
    const unsigned short* __restrict__ imft, // [b][256][row] bf16
    float* __restrict__ out, float invN) {
  __shared__ __align__(16) unsigned short K_lds[32 * 264];    // pad 256+8
  __shared__ __align__(16) unsigned short Vt_lds[256 * 40];   // pad 32+8
  __shared__ __align__(16) unsigned short P_lds[4][16 * 40];  // per-wave

  const int dir = blockIdx.z;
  const unsigned short* Qg  = dir ? imf : tf;
  const unsigned short* Kg  = dir ? tf : imf;
  const unsigned short* Vtg = dir ? tft : imft;

  const int t = threadIdx.x;
  const int l = t & 63;
  const int w = t >> 6;              // 4 waves
  const int h = l >> 4;
  const int q15 = l & 15;
  const int b = blockIdx.x;          // b-major: same-b blocks -> same XCD
  const int qbase = blockIdx.y * 64 + w * 16;
  const size_t qrow0 = (size_t)b * NROW + qbase;
  const size_t kband = (size_t)b * NROW * DD;
  const size_t vband = (size_t)b * DD * NROW;

  // Q fragments: lane holds Q[q15][kc*32 + h*8 + j]
  bf16x8 qf[8];
#pragma unroll
  for (int kc = 0; kc < 8; ++kc)
    qf[kc] = *reinterpret_cast<const bf16x8*>(
        &Qg[(qrow0 + q15) * DD + kc * 32 + h * 8]);

  f32x4 accO[16];
#pragma unroll
  for (int nt = 0; nt < 16; ++nt) accO[nt] = (f32x4){0.f, 0.f, 0.f, 0.f};
  float denom = 0.f;
  float dotq = 0.f;

  for (int c0 = 0; c0 < NROW; c0 += 32) {
    __syncthreads();  // A: all waves done reading previous chunk
#pragma unroll
    for (int i = 0; i < 4; ++i) {  // stage K chunk 32x256 (1024 uint4 / 256 thr)
      const int slot = t + i * 256;
      const int row = slot >> 5, cc = slot & 31;
      const uint4 v = *reinterpret_cast<const uint4*>(
          &Kg[kband + (size_t)(c0 + row) * DD + cc * 8]);
      *reinterpret_cast<uint4*>(&K_lds[row * 264 + cc * 8]) = v;
    }
#pragma unroll
    for (int i = 0; i < 4; ++i) {  // stage Vt chunk 256x32
      const int slot = t + i * 256;
      const int d = slot >> 2, cc = slot & 3;
      const uint4 v = *reinterpret_cast<const uint4*>(
          &Vtg[vband + (size_t)d * NROW + c0 + cc * 8]);
      *reinterpret_cast<uint4*>(&Vt_lds[d * 40 + cc * 8]) = v;
    }
    __syncthreads();  // B: chunk visible

    // ---- swapped QK^T: lane holds S[q=q15][kv=kvt*16+4h+r]
    f32x4 accS[2];
#pragma unroll
    for (int kvt = 0; kvt < 2; ++kvt) accS[kvt] = (f32x4){0.f, 0.f, 0.f, 0.f};
#pragma unroll
    for (int kc = 0; kc < 8; ++kc) {
#pragma unroll
      for (int kvt = 0; kvt < 2; ++kvt) {
        const bf16x8 kf = *reinterpret_cast<const bf16x8*>(
            &K_lds[(kvt * 16 + q15) * 264 + kc * 32 + h * 8]);
        accS[kvt] = __builtin_amdgcn_mfma_f32_16x16x32_bf16(
            kf, qf[kc], accS[kvt], 0, 0, 0);
      }
    }

    // ---- leaky + exp(9a-9); accumulate denom and dot(q,O) = sum p*s_raw
#pragma unroll
    for (int kvt = 0; kvt < 2; ++kvt) {
      float p[4];
#pragma unroll
      for (int r = 0; r < 4; ++r) {
        const float s = accS[kvt][r];
        const float a = (s > 0.f) ? s : 0.1f * s;
        p[r] = __expf(9.f * a - 9.f);
        denom += p[r];
        dotq = fmaf(p[r], s, dotq);
      }
      uint2 pk;
      pk.x = f2bf(p[0]) | ((unsigned)f2bf(p[1]) << 16);
      pk.y = f2bf(p[2]) | ((unsigned)f2bf(p[3]) << 16);
      *reinterpret_cast<uint2*>(
          &P_lds[w][q15 * 40 + kvt * 16 + h * 4]) = pk;
    }

    // ---- PV: O[q][d] += P(16q x 32kv) . V(32kv x 256d)
    const bf16x8 pf = *reinterpret_cast<const bf16x8*>(
        &P_lds[w][q15 * 40 + h * 8]);
#pragma unroll
    for (int nt = 0; nt < 16; ++nt) {
      const bf16x8 vf = *reinterpret_cast<const bf16x8*>(
          &Vt_lds[(nt * 16 + q15) * 40 + h * 8]);
      accO[nt] = __builtin_amdgcn_mfma_f32_16x16x32_bf16(
          pf, vf, accO[nt], 0, 0, 0);
    }
  }

  // ---- epilogue: cos = dotq / (||O|| + denom*eps); mean; atomic
  denom += __shfl_xor(denom, 16, 64);
  denom += __shfl_xor(denom, 32, 64);
  dotq += __shfl_xor(dotq, 16, 64);
  dotq += __shfl_xor(dotq, 32, 64);
  float total = 0.f;
#pragma unroll
  for (int r = 0; r < 4; ++r) {
    float o2 = 0.f;
#pragma unroll
    for (int nt = 0; nt < 16; ++nt) {
      const float ov = accO[nt][r];
      o2 = fmaf(ov, ov, o2);
    }
#pragma unroll
    for (int off = 1; off < 16; off <<= 1) o2 += __shfl_xor(o2, off, 64);
    const int qrow = h * 4 + r;  // q15-index of this C-row's q within tile
    const float dnq = __shfl(denom, qrow, 64);
    const float dq  = __shfl(dotq, qrow, 64);
    total += dq / (sqrtf(o2) + dnq * EPSV);
  }
  total += __shfl_xor(total, 16, 64);
  total += __shfl_xor(total, 32, 64);
  if (l == 0) atomicAdd(&out[b], invN * total);
}

// ---------------------------------------------------------------------------
extern "C" void kernel_launch(void* const* d_in, const int* in_sizes, int n_in,
                              void* d_out, int out_size, void* d_ws, size_t ws_size,
                              hipStream_t stream) {
  const float* text  = (const float*)d_in[0];
  const float* image = (const float*)d_in[1];
  const float* Wt    = (const float*)d_in[2];
  const float* bt    = (const float*)d_in[3];
  const float* Wi    = (const float*)d_in[4];
  const float* bi    = (const float*)d_in[5];
  float* out = (float*)d_out;

  constexpr size_t NE = (size_t)BB * NROW * DD;
  unsigned short* tf   = (unsigned short*)d_ws;  // bf16 row-major
  unsigned short* imf  = tf + NE;
  unsigned short* tft  = imf + NE;               // bf16 [b][d][row]
  unsigned short* imft = tft + NE;
  unsigned short* wtt  = imft + NE;              // Wt text  [256][320]
  unsigned short* wti  = wtt + (size_t)DD * 320; // Wt image [256][1024]

  hipMemsetAsync(out, 0, sizeof(float) * BB, stream);

  prep_w<<<dim3(320 / 32, 8), 256, 0, stream>>>(Wt, wtt, DT, 320);
  prep_w<<<dim3(1024 / 32, 8), 256, 0, stream>>>(Wi, wti, DI, 1024);

  // one projection dispatch: image blocks [0,512) first, text [512,1024)
  proj_mfma_fused<<<dim3(2 * NB), 512, 0, stream>>>(
      image, text, wti, wtt, bi, bt, imf, imft, tf, tft);

  // one attention dispatch, both directions, 4-wave blocks, b-major XCD map
  cross_attn_fused<<<dim3(BB, NROW / 64, 2), 256, 0, stream>>>(
      tf, imf, tft, imft, out, 1.0f / NROW);
}